// Round 10
// baseline (112.150 us; speedup 1.0000x reference)
//
#include <hip/hip_runtime.h>
#include <stdint.h>

#define N_SENT 1024
#define LSEQ   128
#define HDIM   768
#define KSPAN  5
#define TPB    192   // HDIM / 4 float4 lanes
#define G      6     // rows per pipeline group (double-buffered: 6-12 loads in flight)

typedef float f32x4 __attribute__((ext_vector_type(4)));

struct Acc {
    float sx, sy, sz, sw;   // sentence (all rows in range on fast path)
    float px, py, pz, pw;   // span
};

__device__ __forceinline__ void load_group(f32x4* v, const f32x4* frow, int l0, int tid) {
#pragma unroll
    for (int i = 0; i < G; ++i)
        v[i] = __builtin_nontemporal_load(&frow[(size_t)(l0 + i) * (HDIM / 4) + tid]);
}

// Fast path: sentence mask == 1 for every row in range; span mask from bitmask.
__device__ __forceinline__ void consume_fast(const f32x4* v, int l0,
                                             uint64_t m0, uint64_t m1, Acc& a) {
#pragma unroll
    for (int i = 0; i < G; ++i) {
        const int l = l0 + i;
        const uint64_t w = (l < 64) ? m0 : m1;
        const float mp = (float)((w >> (l & 63)) & 1ull);
        a.sx += v[i].x; a.sy += v[i].y; a.sz += v[i].z; a.sw += v[i].w;
        a.px = fmaf(v[i].x, mp, a.px);
        a.py = fmaf(v[i].y, mp, a.py);
        a.pz = fmaf(v[i].z, mp, a.pz);
        a.pw = fmaf(v[i].w, mp, a.pw);
    }
}

__device__ __forceinline__ void set_span_bits(uint64_t& m0, uint64_t& m1, int s, int e) {
    // set bits s..e, 0 <= s <= e <= 127
#pragma unroll
    for (int w = 0; w < 2; ++w) {
        int lo = s - 64 * w, hi = e + 1 - 64 * w;
        lo = lo < 0 ? 0 : (lo > 64 ? 64 : lo);
        hi = hi < 0 ? 0 : (hi > 64 ? 64 : hi);
        if (hi > lo) {
            const int len = hi - lo;
            const uint64_t bits = (len == 64) ? ~0ull : (((1ull << len) - 1ull) << lo);
            if (w == 0) m0 |= bits; else m1 |= bits;
        }
    }
}

__global__ __launch_bounds__(TPB, 6) void bert_pool_kernel(
    const float* __restrict__ review_feat,   // [N, L, H]
    const float* __restrict__ reply_feat,    // [N, L, H]
    const int*   __restrict__ review_nt,     // [N]
    const int*   __restrict__ reply_nt,      // [N]
    const int*   __restrict__ review_ss,     // [N, K]
    const int*   __restrict__ review_se,     // [N, K]
    const int*   __restrict__ reply_ss,      // [N, K]
    const int*   __restrict__ reply_se,      // [N, K]
    float*       __restrict__ out)           // [4, N, H]
{
    const int item = blockIdx.x;             // tensor-interleaved
    const int n    = item >> 1;
    const int tid  = threadIdx.x;
    const bool is_reply = (item & 1) != 0;

    const float* feat = is_reply ? reply_feat : review_feat;
    const int*   ntp  = is_reply ? reply_nt   : review_nt;
    const int*   ssp  = is_reply ? reply_ss   : review_ss;
    const int*   sep  = is_reply ? reply_se   : review_se;
    float* out_pt   = out + (is_reply ? 2 : 0) * (size_t)N_SENT * HDIM;
    float* out_sent = out + (is_reply ? 3 : 1) * (size_t)N_SENT * HDIM;

    const int nt = ntp[n];

    int s[KSPAN], e[KSPAN];
    int l_lo = 1, l_hi = nt;
    uint64_t m0 = 0ull, m1 = 0ull;           // span bitmask over rows 0..127
#pragma unroll
    for (int k = 0; k < KSPAN; ++k) {
        s[k] = ssp[(size_t)n * KSPAN + k];
        e[k] = sep[(size_t)n * KSPAN + k];
        if (s[k] <= e[k]) {
            if (s[k] < l_lo) l_lo = s[k];
            if (e[k] > l_hi) l_hi = e[k];
            int cs = s[k] < 0 ? 0 : s[k];
            int ce = e[k] > LSEQ - 1 ? LSEQ - 1 : e[k];
            if (cs <= ce) set_span_bits(m0, m1, cs, ce);
        }
    }
    if (l_lo < 0) l_lo = 0;
    if (l_hi > LSEQ - 1) l_hi = LSEQ - 1;

    const f32x4* frow = (const f32x4*)(feat + (size_t)n * LSEQ * HDIM);

    Acc a = {0.f,0.f,0.f,0.f, 0.f,0.f,0.f,0.f};
    float span_cnt;

    const bool fast = (l_lo >= 1) && (l_hi <= nt);   // always true for this data

    if (fast) {
        span_cnt = (float)(__popcll(m0) + __popcll(m1));

        const int rows = l_hi - l_lo + 1;
        const int ng   = rows / G;

        f32x4 vA[G], vB[G];
        int g = 0;
        if (ng > 0) load_group(vA, frow, l_lo, tid);
        while (g + 2 <= ng) {
            load_group(vB, frow, l_lo + (g + 1) * G, tid);
            consume_fast(vA, l_lo + g * G, m0, m1, a);
            if (g + 2 < ng) {
                load_group(vA, frow, l_lo + (g + 2) * G, tid);
                consume_fast(vB, l_lo + (g + 1) * G, m0, m1, a);
            } else {
                consume_fast(vB, l_lo + (g + 1) * G, m0, m1, a);
            }
            g += 2;
        }
        if (g < ng) {
            consume_fast(vA, l_lo + g * G, m0, m1, a);
            g++;
        }
        for (int l = l_lo + ng * G; l <= l_hi; ++l) {
            f32x4 v = __builtin_nontemporal_load(&frow[(size_t)l * (HDIM / 4) + tid]);
            const uint64_t w = (l < 64) ? m0 : m1;
            const float mp = (float)((w >> (l & 63)) & 1ull);
            a.sx += v.x; a.sy += v.y; a.sz += v.z; a.sw += v.w;
            a.px = fmaf(v.x, mp, a.px);
            a.py = fmaf(v.y, mp, a.py);
            a.pz = fmaf(v.z, mp, a.pz);
            a.pw = fmaf(v.w, mp, a.pw);
        }
    } else {
        // Generic slow path (not taken for this data): per-row masks.
        span_cnt = 0.f;
        for (int l = l_lo; l <= l_hi; ++l) {
            f32x4 v = frow[(size_t)l * (HDIM / 4) + tid];
            const float ms = (l >= 1 && l <= nt) ? 1.0f : 0.0f;
            bool insp = false;
#pragma unroll
            for (int k = 0; k < KSPAN; ++k)
                insp = insp || ((l >= s[k]) && (l <= e[k]));
            const float mp = insp ? 1.0f : 0.0f;
            a.sx = fmaf(v.x, ms, a.sx);
            a.sy = fmaf(v.y, ms, a.sy);
            a.sz = fmaf(v.z, ms, a.sz);
            a.sw = fmaf(v.w, ms, a.sw);
            a.px = fmaf(v.x, mp, a.px);
            a.py = fmaf(v.y, mp, a.py);
            a.pz = fmaf(v.z, mp, a.pz);
            a.pw = fmaf(v.w, mp, a.pw);
            span_cnt += mp;
        }
    }

    const float sent_cnt = (float)(nt < LSEQ - 1 ? nt : LSEQ - 1);
    const float inv_s = 1.0f / sent_cnt;
    const float smx = a.sx * inv_s, smy = a.sy * inv_s, smz = a.sz * inv_s, smw = a.sw * inv_s;

    const bool  has_span = (span_cnt > 0.5f);
    const float inv_p = 1.0f / fmaxf(span_cnt, 1.0f);
    const float ptx = has_span ? a.px * inv_p : smx;
    const float pty = has_span ? a.py * inv_p : smy;
    const float ptz = has_span ? a.pz * inv_p : smz;
    const float ptw = has_span ? a.pw * inv_p : smw;

    f32x4 rpt = {ptx, pty, ptz, ptw};
    f32x4 rsn = {smx, smy, smz, smw};
    __builtin_nontemporal_store(rpt, &((f32x4*)(out_pt   + (size_t)n * HDIM))[tid]);
    __builtin_nontemporal_store(rsn, &((f32x4*)(out_sent + (size_t)n * HDIM))[tid]);
}

extern "C" void kernel_launch(void* const* d_in, const int* in_sizes, int n_in,
                              void* d_out, int out_size, void* d_ws, size_t ws_size,
                              hipStream_t stream) {
    const float* review_feat = (const float*)d_in[0];
    const float* reply_feat  = (const float*)d_in[1];
    const int*   review_nt   = (const int*)d_in[2];
    const int*   reply_nt    = (const int*)d_in[3];
    const int*   review_ss   = (const int*)d_in[4];
    const int*   review_se   = (const int*)d_in[5];
    const int*   reply_ss    = (const int*)d_in[6];
    const int*   reply_se    = (const int*)d_in[7];
    float* out = (float*)d_out;

    bert_pool_kernel<<<2 * N_SENT, TPB, 0, stream>>>(
        review_feat, reply_feat, review_nt, reply_nt,
        review_ss, review_se, reply_ss, reply_se, out);
}

// Round 11
// 87.181 us; speedup vs baseline: 1.2864x; 1.2864x over previous
//
#include <hip/hip_runtime.h>
#include <stdint.h>

#define N_SENT 1024
#define LSEQ   128
#define HDIM   768
#define KSPAN  5
#define TPB    192   // HDIM / 4 float4 lanes
#define G      6     // rows per pipeline group (double-buffered: 6-12 loads in flight)

typedef float f32x4 __attribute__((ext_vector_type(4)));

struct Acc {
    float sx, sy, sz, sw;   // sentence (all rows in range on fast path)
    float px, py, pz, pw;   // span
};

__device__ __forceinline__ void load_group(f32x4* v, const f32x4* frow, int l0, int tid) {
#pragma unroll
    for (int i = 0; i < G; ++i)
        v[i] = __builtin_nontemporal_load(&frow[(size_t)(l0 + i) * (HDIM / 4) + tid]);
}

// Fast path: sentence mask == 1 for every row in range; span mask from bitmask.
__device__ __forceinline__ void consume_fast(const f32x4* v, int l0,
                                             uint64_t m0, uint64_t m1, Acc& a) {
#pragma unroll
    for (int i = 0; i < G; ++i) {
        const int l = l0 + i;
        const uint64_t w = (l < 64) ? m0 : m1;
        const float mp = (float)((w >> (l & 63)) & 1ull);
        a.sx += v[i].x; a.sy += v[i].y; a.sz += v[i].z; a.sw += v[i].w;
        a.px = fmaf(v[i].x, mp, a.px);
        a.py = fmaf(v[i].y, mp, a.py);
        a.pz = fmaf(v[i].z, mp, a.pz);
        a.pw = fmaf(v[i].w, mp, a.pw);
    }
}

__device__ __forceinline__ void set_span_bits(uint64_t& m0, uint64_t& m1, int s, int e) {
    // set bits s..e, 0 <= s <= e <= 127
#pragma unroll
    for (int w = 0; w < 2; ++w) {
        int lo = s - 64 * w, hi = e + 1 - 64 * w;
        lo = lo < 0 ? 0 : (lo > 64 ? 64 : lo);
        hi = hi < 0 ? 0 : (hi > 64 ? 64 : hi);
        if (hi > lo) {
            const int len = hi - lo;
            const uint64_t bits = (len == 64) ? ~0ull : (((1ull << len) - 1ull) << lo);
            if (w == 0) m0 |= bits; else m1 |= bits;
        }
    }
}

__global__ __launch_bounds__(TPB) void bert_pool_kernel(
    const float* __restrict__ review_feat,   // [N, L, H]
    const float* __restrict__ reply_feat,    // [N, L, H]
    const int*   __restrict__ review_nt,     // [N]
    const int*   __restrict__ reply_nt,      // [N]
    const int*   __restrict__ review_ss,     // [N, K]
    const int*   __restrict__ review_se,     // [N, K]
    const int*   __restrict__ reply_ss,      // [N, K]
    const int*   __restrict__ reply_se,      // [N, K]
    float*       __restrict__ out)           // [4, N, H]
{
    const int item = blockIdx.x;             // tensor-interleaved
    const int n    = item >> 1;
    const int tid  = threadIdx.x;
    const bool is_reply = (item & 1) != 0;

    const float* feat = is_reply ? reply_feat : review_feat;
    const int*   ntp  = is_reply ? reply_nt   : review_nt;
    const int*   ssp  = is_reply ? reply_ss   : review_ss;
    const int*   sep  = is_reply ? reply_se   : review_se;
    float* out_pt   = out + (is_reply ? 2 : 0) * (size_t)N_SENT * HDIM;
    float* out_sent = out + (is_reply ? 3 : 1) * (size_t)N_SENT * HDIM;

    const int nt = ntp[n];

    int s[KSPAN], e[KSPAN];
    int l_lo = 1, l_hi = nt;
    uint64_t m0 = 0ull, m1 = 0ull;           // span bitmask over rows 0..127
#pragma unroll
    for (int k = 0; k < KSPAN; ++k) {
        s[k] = ssp[(size_t)n * KSPAN + k];
        e[k] = sep[(size_t)n * KSPAN + k];
        if (s[k] <= e[k]) {
            if (s[k] < l_lo) l_lo = s[k];
            if (e[k] > l_hi) l_hi = e[k];
            int cs = s[k] < 0 ? 0 : s[k];
            int ce = e[k] > LSEQ - 1 ? LSEQ - 1 : e[k];
            if (cs <= ce) set_span_bits(m0, m1, cs, ce);
        }
    }
    if (l_lo < 0) l_lo = 0;
    if (l_hi > LSEQ - 1) l_hi = LSEQ - 1;

    const f32x4* frow = (const f32x4*)(feat + (size_t)n * LSEQ * HDIM);

    Acc a = {0.f,0.f,0.f,0.f, 0.f,0.f,0.f,0.f};
    float span_cnt;

    const bool fast = (l_lo >= 1) && (l_hi <= nt);   // always true for this data

    if (fast) {
        span_cnt = (float)(__popcll(m0) + __popcll(m1));

        const int rows = l_hi - l_lo + 1;
        const int ng   = rows / G;

        f32x4 vA[G], vB[G];
        int g = 0;
        if (ng > 0) load_group(vA, frow, l_lo, tid);
        while (g + 2 <= ng) {
            load_group(vB, frow, l_lo + (g + 1) * G, tid);
            consume_fast(vA, l_lo + g * G, m0, m1, a);
            if (g + 2 < ng) {
                load_group(vA, frow, l_lo + (g + 2) * G, tid);
                consume_fast(vB, l_lo + (g + 1) * G, m0, m1, a);
            } else {
                consume_fast(vB, l_lo + (g + 1) * G, m0, m1, a);
            }
            g += 2;
        }
        if (g < ng) {
            consume_fast(vA, l_lo + g * G, m0, m1, a);
            g++;
        }
        for (int l = l_lo + ng * G; l <= l_hi; ++l) {
            f32x4 v = __builtin_nontemporal_load(&frow[(size_t)l * (HDIM / 4) + tid]);
            const uint64_t w = (l < 64) ? m0 : m1;
            const float mp = (float)((w >> (l & 63)) & 1ull);
            a.sx += v.x; a.sy += v.y; a.sz += v.z; a.sw += v.w;
            a.px = fmaf(v.x, mp, a.px);
            a.py = fmaf(v.y, mp, a.py);
            a.pz = fmaf(v.z, mp, a.pz);
            a.pw = fmaf(v.w, mp, a.pw);
        }
    } else {
        // Generic slow path (not taken for this data): per-row masks.
        span_cnt = 0.f;
        for (int l = l_lo; l <= l_hi; ++l) {
            f32x4 v = frow[(size_t)l * (HDIM / 4) + tid];
            const float ms = (l >= 1 && l <= nt) ? 1.0f : 0.0f;
            bool insp = false;
#pragma unroll
            for (int k = 0; k < KSPAN; ++k)
                insp = insp || ((l >= s[k]) && (l <= e[k]));
            const float mp = insp ? 1.0f : 0.0f;
            a.sx = fmaf(v.x, ms, a.sx);
            a.sy = fmaf(v.y, ms, a.sy);
            a.sz = fmaf(v.z, ms, a.sz);
            a.sw = fmaf(v.w, ms, a.sw);
            a.px = fmaf(v.x, mp, a.px);
            a.py = fmaf(v.y, mp, a.py);
            a.pz = fmaf(v.z, mp, a.pz);
            a.pw = fmaf(v.w, mp, a.pw);
            span_cnt += mp;
        }
    }

    const float sent_cnt = (float)(nt < LSEQ - 1 ? nt : LSEQ - 1);
    const float inv_s = 1.0f / sent_cnt;
    const float smx = a.sx * inv_s, smy = a.sy * inv_s, smz = a.sz * inv_s, smw = a.sw * inv_s;

    const bool  has_span = (span_cnt > 0.5f);
    const float inv_p = 1.0f / fmaxf(span_cnt, 1.0f);
    const float ptx = has_span ? a.px * inv_p : smx;
    const float pty = has_span ? a.py * inv_p : smy;
    const float ptz = has_span ? a.pz * inv_p : smz;
    const float ptw = has_span ? a.pw * inv_p : smw;

    f32x4 rpt = {ptx, pty, ptz, ptw};
    f32x4 rsn = {smx, smy, smz, smw};
    __builtin_nontemporal_store(rpt, &((f32x4*)(out_pt   + (size_t)n * HDIM))[tid]);
    __builtin_nontemporal_store(rsn, &((f32x4*)(out_sent + (size_t)n * HDIM))[tid]);
}

extern "C" void kernel_launch(void* const* d_in, const int* in_sizes, int n_in,
                              void* d_out, int out_size, void* d_ws, size_t ws_size,
                              hipStream_t stream) {
    const float* review_feat = (const float*)d_in[0];
    const float* reply_feat  = (const float*)d_in[1];
    const int*   review_nt   = (const int*)d_in[2];
    const int*   reply_nt    = (const int*)d_in[3];
    const int*   review_ss   = (const int*)d_in[4];
    const int*   review_se   = (const int*)d_in[5];
    const int*   reply_ss    = (const int*)d_in[6];
    const int*   reply_se    = (const int*)d_in[7];
    float* out = (float*)d_out;

    bert_pool_kernel<<<2 * N_SENT, TPB, 0, stream>>>(
        review_feat, reply_feat, review_nt, reply_nt,
        review_ss, review_se, reply_ss, reply_se, out);
}